// Round 2
// baseline (172.117 us; speedup 1.0000x reference)
//
#include <hip/hip_runtime.h>
#include <math.h>

// NoisyTopkRouter, all-f32 (per reference dtypes).
// x[ntok,384] @ {w_route,w_noise}[8,384]^T -> 16 logits/token,
// noisy = logit + noise*softplus(noise_logit), top-2 of 8, sparse softmax.
// Output: [ntok*8 probs f32 | ntok*2 indices-as-f32].
//
// Layout: wave = 16 tokens x 4 d-slices (lane = tg*4 + c). Each thread
// accumulates 16 expert partial dots over d = {16j + 4c .. +4}; xor-shuffle
// reduce over c; epilogue on c==0 lanes. Weights in LDS (broadcast reads).

constexpr int D  = 384;
constexpr int NW = 16 * D;   // 6144 floats of weights (route then noise)

__global__ __launch_bounds__(256) void noisy_topk_router_f32(
    const float* __restrict__ x,        // [ntok,384]
    const float* __restrict__ noise,    // [ntok,8]
    const float* __restrict__ w_route,  // [8,384]
    const float* __restrict__ b_route,  // [8]
    const float* __restrict__ w_noise,  // [8,384]
    const float* __restrict__ b_noise,  // [8]
    float* __restrict__ out,            // [ntok*8 | ntok*2]
    int ntok)
{
    __shared__ float w_lds[NW];     // [e*384 + d], e 0..7 route, 8..15 noise
    __shared__ float bias[16];

    const int tid = threadIdx.x;

    // stage weights: 6144 f32 = 1536 float4, 256 threads -> 6 each
#pragma unroll
    for (int r = 0; r < 3; ++r) {
        int i = (tid + 256 * r) * 4;                       // < 3072
        *(float4*)(w_lds + i)        = *(const float4*)(w_route + i);
        *(float4*)(w_lds + 3072 + i) = *(const float4*)(w_noise + i);
    }
    if (tid < 8)            bias[tid] = b_route[tid];
    else if (tid < 16)      bias[tid] = b_noise[tid - 8];
    __syncthreads();

    const int wave = tid >> 6;
    const int lane = tid & 63;
    const int tg   = lane >> 2;       // token-in-group 0..15
    const int c    = lane & 3;        // d-slice 0..3
    const int token = blockIdx.x * 64 + wave * 16 + tg;

    float acc[16];
#pragma unroll
    for (int e = 0; e < 16; ++e) acc[e] = 0.f;

    const float* xrow = x + (size_t)token * D;
#pragma unroll 6
    for (int j = 0; j < 24; ++j) {
        const int dbase = j * 16 + c * 4;
        float4 xv = *(const float4*)(xrow + dbase);
#pragma unroll
        for (int e = 0; e < 16; ++e) {
            float4 wv = *(const float4*)(w_lds + e * D + dbase);
            acc[e] += xv.x * wv.x + xv.y * wv.y + xv.z * wv.z + xv.w * wv.w;
        }
    }

    // reduce over the 4 d-slices (lanes c=0..3 within each group of 4)
#pragma unroll
    for (int e = 0; e < 16; ++e) {
        acc[e] += __shfl_xor(acc[e], 1);
        acc[e] += __shfl_xor(acc[e], 2);
    }

    if (c == 0) {
        // noise row: 8 f32 = 32B
        float4 n0 = *(const float4*)(noise + (size_t)token * 8);
        float4 n1 = *(const float4*)(noise + (size_t)token * 8 + 4);
        float nz[8] = {n0.x, n0.y, n0.z, n0.w, n1.x, n1.y, n1.z, n1.w};

        float noisy[8];
#pragma unroll
        for (int e = 0; e < 8; ++e) {
            float lg = acc[e] + bias[e];
            float nl = acc[8 + e] + bias[8 + e];
            // stable softplus: max(z,0) + log1p(exp(-|z|))
            float sp = fmaxf(nl, 0.f) + log1pf(expf(-fabsf(nl)));
            noisy[e] = lg + nz[e] * sp;
        }

        // top-2, jax.lax.top_k tie-break: earliest index wins ties
        float v0 = noisy[0]; int i0 = 0;
#pragma unroll
        for (int e = 1; e < 8; ++e)
            if (noisy[e] > v0) { v0 = noisy[e]; i0 = e; }
        float v1 = -INFINITY; int i1 = 0;
#pragma unroll
        for (int e = 0; e < 8; ++e)
            if (e != i0 && noisy[e] > v1) { v1 = noisy[e]; i1 = e; }

        // 2-way softmax (others exactly 0)
        float ex  = expf(v1 - v0);       // v1 <= v0
        float inv = 1.f / (1.f + ex);
        float p0  = inv;
        float p1  = ex * inv;

        float pr[8];
#pragma unroll
        for (int e = 0; e < 8; ++e)
            pr[e] = (e == i0) ? p0 : ((e == i1) ? p1 : 0.f);

        float* orow = out + (size_t)token * 8;
        *(float4*)(orow)     = make_float4(pr[0], pr[1], pr[2], pr[3]);
        *(float4*)(orow + 4) = make_float4(pr[4], pr[5], pr[6], pr[7]);

        float2 iv = make_float2((float)i0, (float)i1);
        *(float2*)(out + (size_t)ntok * 8 + (size_t)token * 2) = iv;
    }
}

extern "C" void kernel_launch(void* const* d_in, const int* in_sizes, int n_in,
                              void* d_out, int out_size, void* d_ws, size_t ws_size,
                              hipStream_t stream) {
    const float* x       = (const float*)d_in[0];
    const float* noise   = (const float*)d_in[1];
    const float* w_route = (const float*)d_in[2];
    const float* b_route = (const float*)d_in[3];
    const float* w_noise = (const float*)d_in[4];
    const float* b_noise = (const float*)d_in[5];
    float* out = (float*)d_out;

    const int ntok   = in_sizes[0] / D;   // 65536
    const int blocks = ntok / 64;         // 64 tokens per 256-thread block

    hipLaunchKernelGGL(noisy_topk_router_f32, dim3(blocks), dim3(256), 0, stream,
                       x, noise, w_route, b_route, w_noise, b_noise, out, ntok);
}